// Round 3
// baseline (695.834 us; speedup 1.0000x reference)
//
#include <hip/hip_runtime.h>
#include <hip/hip_bf16.h>

#define NN 8192
#define CFEAT 512
#define NCLS 40
#define NPAD 48
#define INDIM 672
#define HIDD 1024

// A8 holds 64*sigmoid (e4m3 normal range [0.43, 63.5]); true normalization
// (d_inv/64) is applied AFTER the MFMA: softmax(D^-1 S c) == softmax((S@c) * d_inv).
#define SC 64.0f
#define INV_SC 0.015625f

typedef __attribute__((ext_vector_type(8))) short bf16x8;
typedef __attribute__((ext_vector_type(4))) float f32x4;

__device__ inline unsigned short f2b(float f) {
  union { __hip_bfloat16 b; unsigned short u; } cv;
  cv.b = __float2bfloat16(f);
  return cv.u;
}

__device__ inline unsigned char f2fp8(float f) {
  int pk = __builtin_amdgcn_cvt_pk_fp8_f32(f, 0.f, 0, false);
  return (unsigned char)(pk & 0xff);
}

// ---------------------------------------------------------------------------
// prep: X -> combined[:, :512] bf16 (vectorized); onehot -> curT0 [48x8192] fp8 (T);
//       W1 -> W1T bf16 ; W2 -> W2T bf16. pad rows of curT/W2T stay poisoned
//       (finite in e4m3fn/bf16, masked downstream).
// ---------------------------------------------------------------------------
__global__ __launch_bounds__(256) void prep_kernel(const float* __restrict__ X,
                                                   const float* __restrict__ onehot,
                                                   const float* __restrict__ W1,
                                                   const float* __restrict__ W2,
                                                   unsigned short* __restrict__ comb,
                                                   unsigned char* __restrict__ curT0,
                                                   unsigned short* __restrict__ W1T,
                                                   unsigned short* __restrict__ W2T) {
  const int NX4 = (NN * CFEAT) / 4;
  const int NO = NCLS * NN;
  const int NW1 = INDIM * HIDD;
  const int NW2 = HIDD * NCLS;
  const int stride = gridDim.x * 256;
  // X path, 4 elems/thread
  for (int idx = blockIdx.x * 256 + threadIdx.x; idx < NX4; idx += stride) {
    float4 x = ((const float4*)X)[idx];
    int e = idx << 2;
    int i = e >> 9, c = e & 511;
    ushort4 o;
    o.x = f2b(x.x); o.y = f2b(x.y); o.z = f2b(x.z); o.w = f2b(x.w);
    *(ushort4*)(comb + (size_t)i * INDIM + c) = o;
  }
  // small tensors, scalar
  const int rest = NO + NW1 + NW2;
  for (int idx = blockIdx.x * 256 + threadIdx.x; idx < rest; idx += stride) {
    if (idx < NO) {
      int c = idx >> 13, i = idx & 8191;
      curT0[(size_t)c * NN + i] = f2fp8(onehot[(size_t)i * NCLS + c]);
    } else if (idx < NO + NW1) {
      int t = idx - NO;
      int k = t >> 10, n = t & 1023;
      W1T[(size_t)n * INDIM + k] = f2b(W1[t]);
    } else {
      int t = idx - NO - NW1;
      int k = t / NCLS, c = t - k * NCLS;
      W2T[(size_t)c * HIDD + k] = f2b(W2[t]);
    }
  }
}

// ---------------------------------------------------------------------------
// normhop: fused normalize + hop0.
// block = 16 rows, 8 waves K-split (1024 each). Streams adj fp32 in MFMA-A
// order, computes sigmoid in registers, accumulates exact fp32 row sums,
// packs 64*sig -> fp8 (written to A8 for hops 1-3), MFMAs vs onehot fp8.
// Epilogue: v = acc * d_inv/64, softmax, write cur1 + comb[:,512:552], d_inv.
// ---------------------------------------------------------------------------
__global__ __launch_bounds__(512) void normhop_kernel(const float* __restrict__ adj,
                                                      const unsigned char* __restrict__ curT,
                                                      unsigned char* __restrict__ A8,
                                                      float* __restrict__ dinv_out,
                                                      unsigned char* __restrict__ nextT,
                                                      unsigned short* __restrict__ comb) {
  __shared__ float red[8][16][NPAD];
  __shared__ float rsum[8][16];
  const int lane = threadIdx.x & 63;
  const int wave = threadIdx.x >> 6;
  const int l15 = lane & 15;
  const int kg = lane >> 4;
  const size_t arow = (size_t)blockIdx.x * 16 + l15;
  const size_t kbase = (size_t)wave * 1024 + (size_t)kg * 8;
  const float4* ap = (const float4*)(adj + arow * NN + kbase);
  unsigned long long* a8out = (unsigned long long*)(A8 + arow * NN + kbase);
  const long* bp0 = (const long*)(curT + (size_t)l15 * NN + kbase);
  const long* bp1 = (const long*)(curT + (size_t)(16 + l15) * NN + kbase);
  const long* bp2 = (const long*)(curT + (size_t)(32 + l15) * NN + kbase);
  f32x4 acc0 = {0.f, 0.f, 0.f, 0.f}, acc1 = {0.f, 0.f, 0.f, 0.f}, acc2 = {0.f, 0.f, 0.f, 0.f};
  float lsum = 0.f;
#pragma unroll 2
  for (int kk = 0; kk < 1024; kk += 32) {
    float4 x0 = ap[0];
    float4 x1 = ap[1];
    ap += 8;  // 32 floats
    float s0 = 1.f / (1.f + __expf(-x0.x));
    float s1 = 1.f / (1.f + __expf(-x0.y));
    float s2 = 1.f / (1.f + __expf(-x0.z));
    float s3 = 1.f / (1.f + __expf(-x0.w));
    float s4 = 1.f / (1.f + __expf(-x1.x));
    float s5 = 1.f / (1.f + __expf(-x1.y));
    float s6 = 1.f / (1.f + __expf(-x1.z));
    float s7 = 1.f / (1.f + __expf(-x1.w));
    lsum += ((s0 + s1) + (s2 + s3)) + ((s4 + s5) + (s6 + s7));
    int w0 = __builtin_amdgcn_cvt_pk_fp8_f32(s0 * SC, s1 * SC, 0, false);
    w0 = __builtin_amdgcn_cvt_pk_fp8_f32(s2 * SC, s3 * SC, w0, true);
    int w1 = __builtin_amdgcn_cvt_pk_fp8_f32(s4 * SC, s5 * SC, 0, false);
    w1 = __builtin_amdgcn_cvt_pk_fp8_f32(s6 * SC, s7 * SC, w1, true);
    unsigned long long afrag = ((unsigned long long)(unsigned int)w1 << 32) | (unsigned int)w0;
    *a8out = afrag;
    a8out += 4;  // 32 bytes
    long a = (long)afrag;
    long b0 = *bp0; bp0 += 4;
    long b1 = *bp1; bp1 += 4;
    long b2 = *bp2; bp2 += 4;
    acc0 = __builtin_amdgcn_mfma_f32_16x16x32_fp8_fp8(a, b0, acc0, 0, 0, 0);
    acc1 = __builtin_amdgcn_mfma_f32_16x16x32_fp8_fp8(a, b1, acc1, 0, 0, 0);
    acc2 = __builtin_amdgcn_mfma_f32_16x16x32_fp8_fp8(a, b2, acc2, 0, 0, 0);
  }
  // row-sum partials: reduce over kg (lane bits 4,5), lane covers row l15
  lsum += __shfl_xor(lsum, 16);
  lsum += __shfl_xor(lsum, 32);
  if (lane < 16) rsum[wave][l15] = lsum;
#pragma unroll
  for (int r = 0; r < 4; ++r) {
    red[wave][kg * 4 + r][l15] = acc0[r];
    red[wave][kg * 4 + r][16 + l15] = acc1[r];
    red[wave][kg * 4 + r][32 + l15] = acc2[r];
  }
  __syncthreads();
  if (wave == 0) {
#pragma unroll
    for (int r = 0; r < 4; ++r) {
      const int rr = kg * 4 + r;
      float v0 = 0.f, v1 = 0.f, v2 = 0.f, rs = 0.f;
#pragma unroll
      for (int w = 0; w < 8; ++w) {
        v0 += red[w][rr][l15];
        v1 += red[w][rr][16 + l15];
        v2 += red[w][rr][32 + l15];
        rs += rsum[w][rr];
      }
      const float dv = 1.f / (rs + 1e-8f);
      const float sc = dv * INV_SC;
      v0 *= sc; v1 *= sc; v2 *= sc;
      const size_t i = (size_t)blockIdx.x * 16 + rr;
      if (l15 == 0) dinv_out[i] = dv;
      const bool ok2 = l15 < 8;  // cols 32..39 valid, 40..47 are padding
      float m = fmaxf(v0, v1);
      if (ok2) m = fmaxf(m, v2);
#pragma unroll
      for (int s = 1; s < 16; s <<= 1) m = fmaxf(m, __shfl_xor(m, s));
      float e0 = __expf(v0 - m);
      float e1 = __expf(v1 - m);
      float e2 = ok2 ? __expf(v2 - m) : 0.f;
      float ssum = e0 + e1 + e2;
#pragma unroll
      for (int s = 1; s < 16; s <<= 1) ssum += __shfl_xor(ssum, s);
      const float inv = 1.f / ssum;
      const float p0 = e0 * inv;
      const float p1 = e1 * inv;
      nextT[(size_t)l15 * NN + i] = f2fp8(p0);
      nextT[(size_t)(16 + l15) * NN + i] = f2fp8(p1);
      const size_t cbase = i * INDIM + CFEAT;
      comb[cbase + l15] = f2b(p0);
      comb[cbase + 16 + l15] = f2b(p1);
      if (ok2) {
        const float p2 = e2 * inv;
        nextT[(size_t)(32 + l15) * NN + i] = f2fp8(p2);
        comb[cbase + 32 + l15] = f2b(p2);
      }
    }
  }
}

// ---------------------------------------------------------------------------
// hop (1..3): next = softmax((A8 @ curT^T) * d_inv/64) ; fp8 MFMA 16x16x32.
// block = 16 rows, 8 waves K-split, LDS reduce + softmax.
// ---------------------------------------------------------------------------
__global__ __launch_bounds__(512) void hop_kernel(const unsigned char* __restrict__ A8,
                                                  const float* __restrict__ dinv,
                                                  const unsigned char* __restrict__ curT,
                                                  unsigned char* __restrict__ nextT,
                                                  unsigned short* __restrict__ comb,
                                                  int hop) {
  __shared__ float red[8][16][NPAD];
  const int lane = threadIdx.x & 63;
  const int wave = threadIdx.x >> 6;
  const int l15 = lane & 15;
  const int kg = lane >> 4;
  const size_t arow = (size_t)blockIdx.x * 16 + l15;
  const size_t kbase = (size_t)wave * 1024 + (size_t)kg * 8;
  const long* ap = (const long*)(A8 + arow * NN + kbase);
  const long* bp0 = (const long*)(curT + (size_t)l15 * NN + kbase);
  const long* bp1 = (const long*)(curT + (size_t)(16 + l15) * NN + kbase);
  const long* bp2 = (const long*)(curT + (size_t)(32 + l15) * NN + kbase);
  f32x4 acc0 = {0.f, 0.f, 0.f, 0.f}, acc1 = {0.f, 0.f, 0.f, 0.f}, acc2 = {0.f, 0.f, 0.f, 0.f};
#pragma unroll 4
  for (int kk = 0; kk < 1024; kk += 32) {
    long a = *ap; ap += 4;
    long b0 = *bp0; bp0 += 4;
    long b1 = *bp1; bp1 += 4;
    long b2 = *bp2; bp2 += 4;
    acc0 = __builtin_amdgcn_mfma_f32_16x16x32_fp8_fp8(a, b0, acc0, 0, 0, 0);
    acc1 = __builtin_amdgcn_mfma_f32_16x16x32_fp8_fp8(a, b1, acc1, 0, 0, 0);
    acc2 = __builtin_amdgcn_mfma_f32_16x16x32_fp8_fp8(a, b2, acc2, 0, 0, 0);
  }
#pragma unroll
  for (int r = 0; r < 4; ++r) {
    red[wave][kg * 4 + r][l15] = acc0[r];
    red[wave][kg * 4 + r][16 + l15] = acc1[r];
    red[wave][kg * 4 + r][32 + l15] = acc2[r];
  }
  __syncthreads();
  if (wave == 0) {
#pragma unroll
    for (int r = 0; r < 4; ++r) {
      const int rr = kg * 4 + r;
      float v0 = 0.f, v1 = 0.f, v2 = 0.f;
#pragma unroll
      for (int w = 0; w < 8; ++w) {
        v0 += red[w][rr][l15];
        v1 += red[w][rr][16 + l15];
        v2 += red[w][rr][32 + l15];
      }
      const size_t i = (size_t)blockIdx.x * 16 + rr;
      const float sc = dinv[i] * INV_SC;
      v0 *= sc; v1 *= sc; v2 *= sc;
      const bool ok2 = l15 < 8;
      float m = fmaxf(v0, v1);
      if (ok2) m = fmaxf(m, v2);
#pragma unroll
      for (int s = 1; s < 16; s <<= 1) m = fmaxf(m, __shfl_xor(m, s));
      float e0 = __expf(v0 - m);
      float e1 = __expf(v1 - m);
      float e2 = ok2 ? __expf(v2 - m) : 0.f;
      float ssum = e0 + e1 + e2;
#pragma unroll
      for (int s = 1; s < 16; s <<= 1) ssum += __shfl_xor(ssum, s);
      const float inv = 1.f / ssum;
      const float p0 = e0 * inv;
      const float p1 = e1 * inv;
      nextT[(size_t)l15 * NN + i] = f2fp8(p0);
      nextT[(size_t)(16 + l15) * NN + i] = f2fp8(p1);
      const size_t cbase = i * INDIM + CFEAT + (size_t)hop * NCLS;
      comb[cbase + l15] = f2b(p0);
      comb[cbase + 16 + l15] = f2b(p1);
      if (ok2) {
        const float p2 = e2 * inv;
        nextT[(size_t)(32 + l15) * NN + i] = f2fp8(p2);
        comb[cbase + 32 + l15] = f2b(p2);
      }
    }
  }
}

// ---------------------------------------------------------------------------
// GEMM1: h = relu(combined @ W1 + b1), bf16 out. tile 64(M) x 128(N), 4 waves.
// ---------------------------------------------------------------------------
__global__ __launch_bounds__(256) void gemm1_kernel(const unsigned short* __restrict__ comb,
                                                    const unsigned short* __restrict__ W1T,
                                                    const float* __restrict__ bias1,
                                                    unsigned short* __restrict__ h) {
  const int lane = threadIdx.x & 63;
  const int wave = threadIdx.x >> 6;
  const int l15 = lane & 15;
  const int kg = lane >> 4;
  const int bm = blockIdx.x & 127;
  const int bn = blockIdx.x >> 7;
  const size_t arow = (size_t)bm * 64 + wave * 16 + l15;
  const bf16x8* ap = (const bf16x8*)(comb + arow * INDIM + (size_t)kg * 8);
  const bf16x8* bp[8];
#pragma unroll
  for (int tt = 0; tt < 8; ++tt)
    bp[tt] = (const bf16x8*)(W1T + (size_t)(bn * 128 + tt * 16 + l15) * INDIM + (size_t)kg * 8);
  f32x4 acc[8] = {};
#pragma unroll 3
  for (int kk = 0; kk < INDIM; kk += 32) {
    bf16x8 a = *ap; ap += 4;
#pragma unroll
    for (int tt = 0; tt < 8; ++tt) {
      bf16x8 b = *bp[tt]; bp[tt] += 4;
      acc[tt] = __builtin_amdgcn_mfma_f32_16x16x32_bf16(a, b, acc[tt], 0, 0, 0);
    }
  }
#pragma unroll
  for (int tt = 0; tt < 8; ++tt) {
    const int n = bn * 128 + tt * 16 + l15;
    const float bv = bias1[n];
#pragma unroll
    for (int r = 0; r < 4; ++r) {
      const size_t i = (size_t)bm * 64 + wave * 16 + kg * 4 + r;
      float v = acc[tt][r] + bv;
      h[i * HIDD + n] = f2b(v > 0.f ? v : 0.f);
    }
  }
}

// ---------------------------------------------------------------------------
// GEMM2: out = h @ W2 + b2 (fp32 out). bf16 MFMA, 4-wave K-split + LDS reduce.
// ---------------------------------------------------------------------------
__global__ __launch_bounds__(256) void gemm2_kernel(const unsigned short* __restrict__ h,
                                                    const unsigned short* __restrict__ W2T,
                                                    const float* __restrict__ bias2,
                                                    float* __restrict__ out) {
  __shared__ float red[4][16][NPAD];
  const int lane = threadIdx.x & 63;
  const int wave = threadIdx.x >> 6;
  const int l15 = lane & 15;
  const int kg = lane >> 4;
  const size_t arow = (size_t)blockIdx.x * 16 + l15;
  const size_t kbase = (size_t)wave * 256 + (size_t)kg * 8;
  const bf16x8* ap = (const bf16x8*)(h + arow * HIDD + kbase);
  const bf16x8* bp0 = (const bf16x8*)(W2T + (size_t)l15 * HIDD + kbase);
  const bf16x8* bp1 = (const bf16x8*)(W2T + (size_t)(16 + l15) * HIDD + kbase);
  const bf16x8* bp2 = (const bf16x8*)(W2T + (size_t)(32 + l15) * HIDD + kbase);
  f32x4 acc0 = {0.f, 0.f, 0.f, 0.f}, acc1 = {0.f, 0.f, 0.f, 0.f}, acc2 = {0.f, 0.f, 0.f, 0.f};
#pragma unroll
  for (int kk = 0; kk < 256; kk += 32) {
    bf16x8 a = *ap; ap += 4;
    bf16x8 vb0 = *bp0; bp0 += 4;
    bf16x8 vb1 = *bp1; bp1 += 4;
    bf16x8 vb2 = *bp2; bp2 += 4;
    acc0 = __builtin_amdgcn_mfma_f32_16x16x32_bf16(a, vb0, acc0, 0, 0, 0);
    acc1 = __builtin_amdgcn_mfma_f32_16x16x32_bf16(a, vb1, acc1, 0, 0, 0);
    acc2 = __builtin_amdgcn_mfma_f32_16x16x32_bf16(a, vb2, acc2, 0, 0, 0);
  }
#pragma unroll
  for (int r = 0; r < 4; ++r) {
    red[wave][kg * 4 + r][l15] = acc0[r];
    red[wave][kg * 4 + r][16 + l15] = acc1[r];
    red[wave][kg * 4 + r][32 + l15] = acc2[r];
  }
  __syncthreads();
  if (wave == 0) {
#pragma unroll
    for (int r = 0; r < 4; ++r) {
      const int rr = kg * 4 + r;
      float v0 = red[0][rr][l15] + red[1][rr][l15] + red[2][rr][l15] + red[3][rr][l15];
      float v1 = red[0][rr][16 + l15] + red[1][rr][16 + l15] + red[2][rr][16 + l15] + red[3][rr][16 + l15];
      float v2 = red[0][rr][32 + l15] + red[1][rr][32 + l15] + red[2][rr][32 + l15] + red[3][rr][32 + l15];
      const size_t i = (size_t)blockIdx.x * 16 + rr;
      out[i * NCLS + l15] = v0 + bias2[l15];
      out[i * NCLS + 16 + l15] = v1 + bias2[16 + l15];
      if (l15 < 8) out[i * NCLS + 32 + l15] = v2 + bias2[32 + l15];
    }
  }
}

extern "C" void kernel_launch(void* const* d_in, const int* in_sizes, int n_in,
                              void* d_out, int out_size, void* d_ws, size_t ws_size,
                              hipStream_t stream) {
  const float* X = (const float*)d_in[0];
  const float* onehot = (const float*)d_in[1];
  const float* adj = (const float*)d_in[2];
  const float* W1 = (const float*)d_in[3];
  const float* b1 = (const float*)d_in[4];
  const float* W2 = (const float*)d_in[5];
  const float* b2 = (const float*)d_in[6];
  float* out = (float*)d_out;
  char* ws = (char*)d_ws;

  // workspace layout (bytes)
  unsigned char*  A8   = (unsigned char*)(ws);                 // 8192*8192*1   = 67108864
  unsigned char*  cur0 = (unsigned char*)(ws + 67108864ull);   // 48*8192*1     = 393216
  unsigned char*  cur1 = (unsigned char*)(ws + 67502080ull);   // 48*8192*1     = 393216
  unsigned short* comb = (unsigned short*)(ws + 67895296ull);  // 8192*672*2    = 11010048
  unsigned short* W1T  = (unsigned short*)(ws + 78905344ull);  // 1024*672*2    = 1376256
  unsigned short* W2T  = (unsigned short*)(ws + 80281600ull);  // 48*1024*2     = 98304
  unsigned short* hbuf = (unsigned short*)(ws + 80379904ull);  // 8192*1024*2   = 16777216
  float*          dinv = (float*)(ws + 97157120ull);           // 8192*4        = 32768
  // total = 97189888 bytes

  prep_kernel<<<2048, 256, 0, stream>>>(X, onehot, W1, W2, comb, cur0, W1T, W2T);
  normhop_kernel<<<NN / 16, 512, 0, stream>>>(adj, cur0, A8, dinv, cur1, comb);
  hop_kernel<<<NN / 16, 512, 0, stream>>>(A8, dinv, cur1, cur0, comb, 1);
  hop_kernel<<<NN / 16, 512, 0, stream>>>(A8, dinv, cur0, cur1, comb, 2);
  hop_kernel<<<NN / 16, 512, 0, stream>>>(A8, dinv, cur1, cur0, comb, 3);
  gemm1_kernel<<<1024, 256, 0, stream>>>(comb, W1T, b1, hbuf);
  gemm2_kernel<<<NN / 16, 256, 0, stream>>>(hbuf, W2T, b2, out);
}